// Round 7
// baseline (744.188 us; speedup 1.0000x reference)
//
#include <hip/hip_runtime.h>

typedef __bf16 bf16x8 __attribute__((ext_vector_type(8)));
typedef float f32x4 __attribute__((ext_vector_type(4)));
typedef unsigned short us8 __attribute__((ext_vector_type(8)));

constexpr int NN = 50000;   // nodes
constexpr int NE = 800000;  // edges
constexpr int NNP = NN + 8;           // slice row stride (row NN = zero row)
constexpr int NEP = NE + 8 * NN;      // padded CSR capacity (1.2M slots)
constexpr int DIN = 256, DHID = 256, DOUT = 128;
constexpr int NCH = (NN + 255) / 256;  // 196 chunks of 256
constexpr int NGRP = (NN + 63) / 64;   // 782 groups of 64 nodes
constexpr int RNG = 6250;              // nodes per XCD dst-range (50000/8)

__device__ __forceinline__ unsigned short f2bf(float f) {
  unsigned u = __float_as_uint(f);
  u += 0x7fffu + ((u >> 16) & 1u);  // RNE
  return (unsigned short)(u >> 16);
}

// accumulate 8 bf16 (packed in uint4) into a[8]
__device__ __forceinline__ void acc8(float a[8], uint4 v) {
  a[0] += __uint_as_float(v.x << 16);
  a[1] += __uint_as_float(v.x & 0xffff0000u);
  a[2] += __uint_as_float(v.y << 16);
  a[3] += __uint_as_float(v.y & 0xffff0000u);
  a[4] += __uint_as_float(v.z << 16);
  a[5] += __uint_as_float(v.z & 0xffff0000u);
  a[6] += __uint_as_float(v.w << 16);
  a[7] += __uint_as_float(v.w & 0xffff0000u);
}

// ---------------- pad helpers ----------------

__global__ void fillcol_kernel(unsigned short* __restrict__ col) {
  constexpr int TOT = 2 * NEP / 8;  // uint4 count
  int i = blockIdx.x * blockDim.x + threadIdx.x;
  unsigned v = (unsigned)NN | ((unsigned)NN << 16);
  if (i < TOT) ((uint4*)col)[i] = (uint4){v, v, v, v};
}

// zero row NN of each of the 16 chunk slices (serves m1c and m2c phases)
__global__ void zrow_kernel(unsigned short* __restrict__ m1c) {
  int t = threadIdx.x;  // 512 threads = 16 slices x 32 cols
  int s = t >> 5, c = t & 31;
  m1c[(size_t)s * NNP * 32 + (size_t)NN * 32 + c] = 0;
}

// ---------------- CSR build (XCD-partitioned by dst-range) ----------------

__global__ void hist_kernel(const int* __restrict__ e0, const int* __restrict__ e1,
                            int* __restrict__ counts) {
  int g = blockIdx.y;
  const int* dst = (g ? e1 : e0) + NE;  // edge_index row 1
  int* c = counts + g * NN;
  int r = blockIdx.x & 7;
  int t = (blockIdx.x >> 3) * blockDim.x + threadIdx.x;
  int stride = (gridDim.x >> 3) * blockDim.x;
  for (int i = t; i < NE; i += stride) {
    int d = dst[i];
    if (d / RNG == r) atomicAdd(&c[d], 1);
  }
}

__global__ void scatter_kernel(const int* __restrict__ e0, const int* __restrict__ e1,
                               int* __restrict__ cursor, unsigned short* __restrict__ col) {
  int g = blockIdx.y;
  const int* e = g ? e1 : e0;
  int* cur = cursor + g * NN;
  unsigned short* cl = col + (size_t)g * NEP;
  int r = blockIdx.x & 7;
  int t = (blockIdx.x >> 3) * blockDim.x + threadIdx.x;
  int stride = (gridDim.x >> 3) * blockDim.x;
  for (int i = t; i < NE; i += stride) {
    int d = e[NE + i];
    if (d / RNG == r) {
      int s = e[i];
      int slot = atomicAdd(&cur[d], 1);
      cl[slot] = (unsigned short)s;
    }
  }
}

__global__ __launch_bounds__(256) void scanA_kernel(const int* __restrict__ counts,
                                                    int* __restrict__ bsum) {
  int g = blockIdx.y, chunk = blockIdx.x, t = threadIdx.x;
  int i = chunk * 256 + t;
  int v = (i < NN) ? ((counts[g * NN + i] + 7) & ~7) : 0;  // padded
  __shared__ int sh[256];
  sh[t] = v;
  __syncthreads();
  for (int off = 128; off > 0; off >>= 1) {
    if (t < off) sh[t] += sh[t + off];
    __syncthreads();
  }
  if (t == 0) bsum[g * NCH + chunk] = sh[0];
}

__global__ __launch_bounds__(256) void scanB_kernel(int* __restrict__ bsum,
                                                    int* __restrict__ rowptr) {
  int g = blockIdx.x, t = threadIdx.x;
  int v = (t < NCH) ? bsum[g * NCH + t] : 0;
  __shared__ int sh[256];
  sh[t] = v;
  __syncthreads();
  for (int off = 1; off < 256; off <<= 1) {
    int x = (t >= off) ? sh[t - off] : 0;
    __syncthreads();
    if (t >= off) sh[t] += x;
    __syncthreads();
  }
  if (t < NCH) bsum[g * NCH + t] = sh[t] - v;  // exclusive base
  if (t == 255) rowptr[g * (NN + 1) + NN] = sh[255];
}

__global__ __launch_bounds__(256) void scanC_kernel(const int* __restrict__ counts,
                                                    const int* __restrict__ bsum,
                                                    int* __restrict__ rowptr,
                                                    int* __restrict__ cursor,
                                                    float* __restrict__ dinv) {
  int g = blockIdx.y, chunk = blockIdx.x, t = threadIdx.x;
  int i = chunk * 256 + t;
  int c = (i < NN) ? counts[g * NN + i] : 0;
  int v = (c + 7) & ~7;  // padded
  __shared__ int sh[256];
  sh[t] = v;
  __syncthreads();
  for (int off = 1; off < 256; off <<= 1) {
    int x = (t >= off) ? sh[t - off] : 0;
    __syncthreads();
    if (t >= off) sh[t] += x;
    __syncthreads();
  }
  if (i < NN) {
    int run = bsum[g * NCH + chunk] + sh[t] - v;
    rowptr[g * (NN + 1) + i] = run;
    cursor[g * NN + i] = run;
    dinv[g * NN + i] = rsqrtf((float)(c + 1));  // true degree +1 self-loop
  }
}

// ---------------- Pack W into B-fragment order ----------------
// Wpack flat index: ((kb*NT + nt)*64 + lane)*8 + j  holds W[kb*32 + (lane>>4)*8 + j][nt*16 + (lane&15)]

__global__ void pack_kernel(const float* __restrict__ W1, const float* __restrict__ W2,
                            unsigned short* __restrict__ P1, unsigned short* __restrict__ P2) {
  int i = blockIdx.x * blockDim.x + threadIdx.x;
  constexpr int N1 = 8 * 16 * 64 * 8;  // 65536 (K=256, N=256)
  constexpr int N2 = 8 * 8 * 64 * 8;   // 32768 (K=256, N=128)
  if (i < N1) {
    int j = i & 7, lane = (i >> 3) & 63, grp = i >> 9;
    int nt = grp & 15, kb = grp >> 4;
    int k = kb * 32 + (lane >> 4) * 8 + j;
    int n = nt * 16 + (lane & 15);
    P1[i] = f2bf(W1[k * DHID + n]);
  } else if (i < N1 + N2) {
    int ii = i - N1;
    int j = ii & 7, lane = (ii >> 3) & 63, grp = ii >> 9;
    int nt = grp & 7, kb = grp >> 3;
    int k = kb * 32 + (lane >> 4) * 8 + j;
    int n = nt * 16 + (lane & 15);
    P2[ii] = f2bf(W2[k * DOUT + n]);
  }
}

// ---------------- mm1: m1c = (x @ W1) * dinv[row], CHUNK-MAJOR bf16 ----------------
// W1-pack (128 KB) staged in LDS once per block; 8 waves grid-stride over
// 16-row tiles. Per tile: all 16 A float4 loads issued up-front (one HBM
// round-trip), 128 MFMAs read B via conflict-free ds_read_b128.
// m1c layout: [g][chunk 0..7][node (NNP rows)][32 cols]; chunk = col>>5.

__global__ __launch_bounds__(512, 2) void mm1_kernel(
    const float* __restrict__ A0, const float* __restrict__ A1,
    const unsigned short* __restrict__ Wp, unsigned short* __restrict__ m1c,
    const float* __restrict__ dinv) {
  constexpr int NT = 16, K = 256;
  __shared__ unsigned short Bsh[8 * NT * 64 * 8];  // 128 KB
  int g = blockIdx.y;
  const float* A = g ? A1 : A0;
  unsigned short* C = m1c + (size_t)g * 8 * NNP * 32;
  const float* dv = dinv + g * NN;
  for (int i = threadIdx.x; i < 8 * NT * 64; i += 512)
    ((uint4*)Bsh)[i] = ((const uint4*)Wp)[i];
  __syncthreads();
  int wave = threadIdx.x >> 6, lane = threadIdx.x & 63;
  int q = lane >> 4, lm = lane & 15;
  int mstride = gridDim.x * 128;
  for (int m0 = blockIdx.x * 128 + wave * 16; m0 < NN; m0 += mstride) {
    int rowc = min(m0 + lm, NN - 1);
    const float* Ab = A + (size_t)rowc * K + q * 8;
    float4 ra[8], rb[8];
#pragma unroll
    for (int kb = 0; kb < 8; kb++) {
      ra[kb] = *(const float4*)(Ab + kb * 32);
      rb[kb] = *(const float4*)(Ab + kb * 32 + 4);
    }
    f32x4 acc[NT];
#pragma unroll
    for (int nt = 0; nt < NT; nt++) acc[nt] = (f32x4){0.f, 0.f, 0.f, 0.f};
#pragma unroll
    for (int kb = 0; kb < 8; kb++) {
      bf16x8 af;
      af[0] = (__bf16)ra[kb].x; af[1] = (__bf16)ra[kb].y;
      af[2] = (__bf16)ra[kb].z; af[3] = (__bf16)ra[kb].w;
      af[4] = (__bf16)rb[kb].x; af[5] = (__bf16)rb[kb].y;
      af[6] = (__bf16)rb[kb].z; af[7] = (__bf16)rb[kb].w;
#pragma unroll
      for (int nt = 0; nt < NT; nt++) {
        bf16x8 b = *(const bf16x8*)(Bsh + (((size_t)kb * NT + nt) * 64 + lane) * 8);
        acc[nt] = __builtin_amdgcn_mfma_f32_16x16x32_bf16(af, b, acc[nt], 0, 0, 0);
      }
    }
    float dvr[4];
#pragma unroll
    for (int r = 0; r < 4; r++) dvr[r] = dv[min(m0 + q * 4 + r, NN - 1)];
#pragma unroll
    for (int nt = 0; nt < NT; nt++) {
#pragma unroll
      for (int r = 0; r < 4; r++) {
        int grow = m0 + q * 4 + r;
        if (grow < NN)
          C[((size_t)(nt >> 1) * NNP + grow) * 32 + (nt & 1) * 16 + lm] =
              f2bf(acc[nt][r] * dvr[r]);
      }
    }
  }
}

// ---------------- agg1c: XCD-sharded group-per-node gather (32-col chunk) --------

__global__ __launch_bounds__(256) void agg1c_kernel(
    const unsigned short* __restrict__ m1c, unsigned short* __restrict__ a1c,
    const int* __restrict__ rowptr, const unsigned short* __restrict__ col,
    const float* __restrict__ dinv, const float* __restrict__ b1) {
  int chunk = blockIdx.x & 7, nb = blockIdx.x >> 3, g = blockIdx.y;
  const unsigned short* Hc = m1c + ((size_t)g * 8 + chunk) * ((size_t)NNP * 32);
  unsigned short* Ac = a1c + ((size_t)g * 8 + chunk) * ((size_t)NNP * 32);
  const int* rp = rowptr + g * (NN + 1);
  const unsigned short* cl = col + (size_t)g * NEP;
  const float* dv = dinv + g * NN;
  int lane = threadIdx.x & 63, wave = threadIdx.x >> 6;
  int sub = lane & 3;
  int node = nb * 64 + wave * 16 + (lane >> 2);
  int nodec = min(node, NN - 1);
  float4 bb0 = *(const float4*)(b1 + chunk * 32 + sub * 8);
  float4 bb1 = *(const float4*)(b1 + chunk * 32 + sub * 8 + 4);
  int jb = rp[nodec], je = rp[nodec + 1];
  float a[8] = {0.f, 0.f, 0.f, 0.f, 0.f, 0.f, 0.f, 0.f};
  // self row
  uint4 sv = *(const uint4*)(Hc + (size_t)nodec * 32 + sub * 8);
  acc8(a, sv);
  for (int j = jb; j < je; j += 8) {
    uint4 w = *(const uint4*)(cl + j);  // 8 indices, 16B aligned (jb,j mult of 8)
    int s0 = w.x & 0xffff, s1 = w.x >> 16;
    int s2 = w.y & 0xffff, s3 = w.y >> 16;
    int s4 = w.z & 0xffff, s5 = w.z >> 16;
    int s6 = w.w & 0xffff, s7 = w.w >> 16;
    uint4 v0 = *(const uint4*)(Hc + s0 * 32 + sub * 8);
    uint4 v1 = *(const uint4*)(Hc + s1 * 32 + sub * 8);
    uint4 v2 = *(const uint4*)(Hc + s2 * 32 + sub * 8);
    uint4 v3 = *(const uint4*)(Hc + s3 * 32 + sub * 8);
    uint4 v4 = *(const uint4*)(Hc + s4 * 32 + sub * 8);
    uint4 v5 = *(const uint4*)(Hc + s5 * 32 + sub * 8);
    uint4 v6 = *(const uint4*)(Hc + s6 * 32 + sub * 8);
    uint4 v7 = *(const uint4*)(Hc + s7 * 32 + sub * 8);
    acc8(a, v0); acc8(a, v1); acc8(a, v2); acc8(a, v3);
    acc8(a, v4); acc8(a, v5); acc8(a, v6); acc8(a, v7);
  }
  float di = dv[nodec];
  us8 o;
  o[0] = f2bf(fmaxf(fmaf(a[0], di, bb0.x), 0.f));
  o[1] = f2bf(fmaxf(fmaf(a[1], di, bb0.y), 0.f));
  o[2] = f2bf(fmaxf(fmaf(a[2], di, bb0.z), 0.f));
  o[3] = f2bf(fmaxf(fmaf(a[3], di, bb0.w), 0.f));
  o[4] = f2bf(fmaxf(fmaf(a[4], di, bb1.x), 0.f));
  o[5] = f2bf(fmaxf(fmaf(a[5], di, bb1.y), 0.f));
  o[6] = f2bf(fmaxf(fmaf(a[6], di, bb1.z), 0.f));
  o[7] = f2bf(fmaxf(fmaf(a[7], di, bb1.w), 0.f));
  if (node < NN) *(us8*)(Ac + (size_t)node * 32 + sub * 8) = o;
}

// ---------------- mm2: m2c = (a1 @ W2) * dinv, dense GEMM ----------------
// W2-pack (64 KB) staged in LDS; 8 waves grid-stride over 16-row tiles.
// a1c chunk-major IS the A-frag layout. m2c chunk-major: [g][chunk 0..3][node][32].

__global__ __launch_bounds__(512, 2) void mm2_kernel(
    const unsigned short* __restrict__ a1c, const unsigned short* __restrict__ P2,
    unsigned short* __restrict__ m2c, const float* __restrict__ dinv) {
  constexpr int NT2 = DOUT / 16;  // 8
  __shared__ unsigned short Bsh[8 * NT2 * 64 * 8];  // 64 KB
  int g = blockIdx.y;
  const unsigned short* A = a1c + (size_t)g * 8 * NNP * 32;
  unsigned short* C = m2c + (size_t)g * 4 * NNP * 32;
  const float* dv = dinv + g * NN;
  for (int i = threadIdx.x; i < 8 * NT2 * 64; i += 512)
    ((uint4*)Bsh)[i] = ((const uint4*)P2)[i];
  __syncthreads();
  int wave = threadIdx.x >> 6, lane = threadIdx.x & 63;
  int q = lane >> 4, lm = lane & 15;
  int mstride = gridDim.x * 128;
  for (int m0 = blockIdx.x * 128 + wave * 16; m0 < NN; m0 += mstride) {
    int rowc = min(m0 + lm, NN - 1);
    bf16x8 af[8];
#pragma unroll
    for (int kb = 0; kb < 8; kb++)
      af[kb] = *(const bf16x8*)(A + ((size_t)kb * NNP + rowc) * 32 + q * 8);
    f32x4 acc[NT2];
#pragma unroll
    for (int nt = 0; nt < NT2; nt++) acc[nt] = (f32x4){0.f, 0.f, 0.f, 0.f};
#pragma unroll
    for (int kb = 0; kb < 8; kb++) {
#pragma unroll
      for (int nt = 0; nt < NT2; nt++) {
        bf16x8 b = *(const bf16x8*)(Bsh + (((size_t)kb * NT2 + nt) * 64 + lane) * 8);
        acc[nt] = __builtin_amdgcn_mfma_f32_16x16x32_bf16(af[kb], b, acc[nt], 0, 0, 0);
      }
    }
    float dvr[4];
#pragma unroll
    for (int r = 0; r < 4; r++) dvr[r] = dv[min(m0 + q * 4 + r, NN - 1)];
#pragma unroll
    for (int nt = 0; nt < NT2; nt++) {
#pragma unroll
      for (int r = 0; r < 4; r++) {
        int grow = m0 + q * 4 + r;
        if (grow < NN)
          C[((size_t)(nt >> 1) * NNP + grow) * 32 + (nt & 1) * 16 + lm] =
              f2bf(acc[nt][r] * dvr[r]);
      }
    }
  }
}

// ---------------- agg2c: XCD-sharded group-per-node final aggregate -> out ------

__global__ __launch_bounds__(256) void agg2c_kernel(
    const unsigned short* __restrict__ m2c, float* __restrict__ out,
    const int* __restrict__ rowptr, const unsigned short* __restrict__ col,
    const float* __restrict__ dinv, const float* __restrict__ b2) {
  int chunk = blockIdx.x & 3, nb = blockIdx.x >> 2, g = blockIdx.y;
  const unsigned short* Hc = m2c + ((size_t)g * 4 + chunk) * ((size_t)NNP * 32);
  float* O = out + (size_t)g * NN * DOUT;
  const int* rp = rowptr + g * (NN + 1);
  const unsigned short* cl = col + (size_t)g * NEP;
  const float* dv = dinv + g * NN;
  int lane = threadIdx.x & 63, wave = threadIdx.x >> 6;
  int sub = lane & 3;
  int node = nb * 64 + wave * 16 + (lane >> 2);
  int nodec = min(node, NN - 1);
  float4 c0 = *(const float4*)(b2 + chunk * 32 + sub * 8);
  float4 c1 = *(const float4*)(b2 + chunk * 32 + sub * 8 + 4);
  int jb = rp[nodec], je = rp[nodec + 1];
  float a[8] = {0.f, 0.f, 0.f, 0.f, 0.f, 0.f, 0.f, 0.f};
  uint4 sv = *(const uint4*)(Hc + (size_t)nodec * 32 + sub * 8);
  acc8(a, sv);
  for (int j = jb; j < je; j += 8) {
    uint4 w = *(const uint4*)(cl + j);
    int s0 = w.x & 0xffff, s1 = w.x >> 16;
    int s2 = w.y & 0xffff, s3 = w.y >> 16;
    int s4 = w.z & 0xffff, s5 = w.z >> 16;
    int s6 = w.w & 0xffff, s7 = w.w >> 16;
    uint4 v0 = *(const uint4*)(Hc + s0 * 32 + sub * 8);
    uint4 v1 = *(const uint4*)(Hc + s1 * 32 + sub * 8);
    uint4 v2 = *(const uint4*)(Hc + s2 * 32 + sub * 8);
    uint4 v3 = *(const uint4*)(Hc + s3 * 32 + sub * 8);
    uint4 v4 = *(const uint4*)(Hc + s4 * 32 + sub * 8);
    uint4 v5 = *(const uint4*)(Hc + s5 * 32 + sub * 8);
    uint4 v6 = *(const uint4*)(Hc + s6 * 32 + sub * 8);
    uint4 v7 = *(const uint4*)(Hc + s7 * 32 + sub * 8);
    acc8(a, v0); acc8(a, v1); acc8(a, v2); acc8(a, v3);
    acc8(a, v4); acc8(a, v5); acc8(a, v6); acc8(a, v7);
  }
  if (node < NN) {
    float di = dv[node];
    float4 o0, o1;
    o0.x = fmaf(a[0], di, c0.x); o0.y = fmaf(a[1], di, c0.y);
    o0.z = fmaf(a[2], di, c0.z); o0.w = fmaf(a[3], di, c0.w);
    o1.x = fmaf(a[4], di, c1.x); o1.y = fmaf(a[5], di, c1.y);
    o1.z = fmaf(a[6], di, c1.z); o1.w = fmaf(a[7], di, c1.w);
    *(float4*)(O + (size_t)node * DOUT + chunk * 32 + sub * 8) = o0;
    *(float4*)(O + (size_t)node * DOUT + chunk * 32 + sub * 8 + 4) = o1;
  }
}

// ---------------- launch ----------------

extern "C" void kernel_launch(void* const* d_in, const int* in_sizes, int n_in,
                              void* d_out, int out_size, void* d_ws, size_t ws_size,
                              hipStream_t stream) {
  const float* x1 = (const float*)d_in[0];
  const int* e1 = (const int*)d_in[1];
  const float* x2 = (const float*)d_in[2];
  const int* e2 = (const int*)d_in[3];
  const float* W1 = (const float*)d_in[4];
  const float* b1 = (const float*)d_in[5];
  const float* W2 = (const float*)d_in[6];
  const float* b2 = (const float*)d_in[7];
  float* out = (float*)d_out;

  char* base = (char*)d_ws;
  size_t off = 0;
  auto alloc = [&](size_t bytes) -> void* {
    void* p = base + off;
    off = (off + bytes + 511) & ~(size_t)511;
    return p;
  };
  int* counts = (int*)alloc((size_t)2 * NN * 4);
  int* rowptr = (int*)alloc((size_t)2 * (NN + 1) * 4);
  int* cursor = (int*)alloc((size_t)2 * NN * 4);
  float* dinv = (float*)alloc((size_t)2 * NN * 4);
  int* bsum = (int*)alloc((size_t)2 * NCH * 4);
  unsigned short* col = (unsigned short*)alloc((size_t)2 * NEP * 2);
  unsigned short* m1c = (unsigned short*)alloc((size_t)2 * 8 * NNP * 32 * 2);
  unsigned short* a1c = (unsigned short*)alloc((size_t)2 * 8 * NNP * 32 * 2);
  unsigned short* m2c = m1c;  // reuse: m1c dead after agg1c; zero rows preserved
  unsigned short* P1 = (unsigned short*)alloc((size_t)8 * 16 * 64 * 8 * 2);
  unsigned short* P2 = (unsigned short*)alloc((size_t)8 * 8 * 64 * 8 * 2);

  fillcol_kernel<<<(2 * NEP / 8 + 255) / 256, 256, 0, stream>>>(col);
  hipMemsetAsync(counts, 0, (size_t)2 * NN * 4, stream);
  // XCD-partitioned hist: 8 ranges x 96 slices
  hist_kernel<<<dim3(8 * 96, 2), 256, 0, stream>>>(e1, e2, counts);
  scanA_kernel<<<dim3(NCH, 2), 256, 0, stream>>>(counts, bsum);
  scanB_kernel<<<2, 256, 0, stream>>>(bsum, rowptr);
  scanC_kernel<<<dim3(NCH, 2), 256, 0, stream>>>(counts, bsum, rowptr, cursor, dinv);
  // XCD-partitioned scatter: cursor + cl region per dst-range stay in one L2
  scatter_kernel<<<dim3(8 * 96, 2), 256, 0, stream>>>(e1, e2, cursor, col);
  pack_kernel<<<(98304 + 255) / 256, 256, 0, stream>>>(W1, W2, P1, P2);
  zrow_kernel<<<1, 512, 0, stream>>>(m1c);
  // layer 1 mm: m1c = (x @ W1) * dinv (bf16, chunk-major), W1-pack in LDS
  mm1_kernel<<<dim3(128, 2), 512, 0, stream>>>(x1, x2, P1, m1c, dinv);
  // sharded agg1: a1c = relu(agg(m1c)*dinv + b1) per 32-col chunk (XCD-local)
  agg1c_kernel<<<dim3(8 * NGRP, 2), 256, 0, stream>>>(m1c, a1c, rowptr, col, dinv, b1);
  // layer 2 mm: m2c = (a1 @ W2) * dinv (bf16, chunk-major), W2-pack in LDS
  mm2_kernel<<<dim3(256, 2), 512, 0, stream>>>(a1c, P2, m2c, dinv);
  // sharded agg2: out = agg(m2c)*dinv + b2 (f32)
  agg2c_kernel<<<dim3(4 * NGRP, 2), 256, 0, stream>>>(m2c, out, rowptr, col, dinv, b2);
}

// Round 8
// 484.336 us; speedup vs baseline: 1.5365x; 1.5365x over previous
//
#include <hip/hip_runtime.h>

typedef __bf16 bf16x8 __attribute__((ext_vector_type(8)));
typedef float f32x4 __attribute__((ext_vector_type(4)));
typedef unsigned short us8 __attribute__((ext_vector_type(8)));

constexpr int NN = 50000;   // nodes
constexpr int NE = 800000;  // edges
constexpr int NNP = NN + 8;           // slice row stride (row NN = zero row)
constexpr int NEP = NE + 8 * NN;      // padded CSR capacity (1.2M slots)
constexpr int DIN = 256, DHID = 256, DOUT = 128;
constexpr int NCH = (NN + 255) / 256;  // 196 chunks of 256
constexpr int NGRP = (NN + 63) / 64;   // 782 groups of 64 nodes
constexpr int RNG = 6250;              // nodes per XCD dst-range (50000/8)

__device__ __forceinline__ unsigned short f2bf(float f) {
  unsigned u = __float_as_uint(f);
  u += 0x7fffu + ((u >> 16) & 1u);  // RNE
  return (unsigned short)(u >> 16);
}

// accumulate 8 bf16 (packed in uint4) into a[8]
__device__ __forceinline__ void acc8(float a[8], uint4 v) {
  a[0] += __uint_as_float(v.x << 16);
  a[1] += __uint_as_float(v.x & 0xffff0000u);
  a[2] += __uint_as_float(v.y << 16);
  a[3] += __uint_as_float(v.y & 0xffff0000u);
  a[4] += __uint_as_float(v.z << 16);
  a[5] += __uint_as_float(v.z & 0xffff0000u);
  a[6] += __uint_as_float(v.w << 16);
  a[7] += __uint_as_float(v.w & 0xffff0000u);
}

// ---------------- pad helpers ----------------

__global__ void fillcol_kernel(unsigned short* __restrict__ col) {
  constexpr int TOT = 2 * NEP / 8;  // uint4 count
  int i = blockIdx.x * blockDim.x + threadIdx.x;
  unsigned v = (unsigned)NN | ((unsigned)NN << 16);
  if (i < TOT) ((uint4*)col)[i] = (uint4){v, v, v, v};
}

// zero row NN of each of the 16 chunk slices (serves m1c and m2c phases)
__global__ void zrow_kernel(unsigned short* __restrict__ m1c) {
  int t = threadIdx.x;  // 512 threads = 16 slices x 32 cols
  int s = t >> 5, c = t & 31;
  m1c[(size_t)s * NNP * 32 + (size_t)NN * 32 + c] = 0;
}

// ---------------- CSR build (XCD-partitioned by dst-range) ----------------

__global__ void hist_kernel(const int* __restrict__ e0, const int* __restrict__ e1,
                            int* __restrict__ counts) {
  int g = blockIdx.y;
  const int* dst = (g ? e1 : e0) + NE;  // edge_index row 1
  int* c = counts + g * NN;
  int r = blockIdx.x & 7;
  int t = (blockIdx.x >> 3) * blockDim.x + threadIdx.x;
  int stride = (gridDim.x >> 3) * blockDim.x;
  for (int i = t; i < NE; i += stride) {
    int d = dst[i];
    if (d / RNG == r) atomicAdd(&c[d], 1);
  }
}

__global__ void scatter_kernel(const int* __restrict__ e0, const int* __restrict__ e1,
                               int* __restrict__ cursor, unsigned short* __restrict__ col) {
  int g = blockIdx.y;
  const int* e = g ? e1 : e0;
  int* cur = cursor + g * NN;
  unsigned short* cl = col + (size_t)g * NEP;
  int r = blockIdx.x & 7;
  int t = (blockIdx.x >> 3) * blockDim.x + threadIdx.x;
  int stride = (gridDim.x >> 3) * blockDim.x;
  for (int i = t; i < NE; i += stride) {
    int d = e[NE + i];
    if (d / RNG == r) {
      int s = e[i];
      int slot = atomicAdd(&cur[d], 1);
      cl[slot] = (unsigned short)s;
    }
  }
}

__global__ __launch_bounds__(256) void scanA_kernel(const int* __restrict__ counts,
                                                    int* __restrict__ bsum) {
  int g = blockIdx.y, chunk = blockIdx.x, t = threadIdx.x;
  int i = chunk * 256 + t;
  int v = (i < NN) ? ((counts[g * NN + i] + 7) & ~7) : 0;  // padded
  __shared__ int sh[256];
  sh[t] = v;
  __syncthreads();
  for (int off = 128; off > 0; off >>= 1) {
    if (t < off) sh[t] += sh[t + off];
    __syncthreads();
  }
  if (t == 0) bsum[g * NCH + chunk] = sh[0];
}

__global__ __launch_bounds__(256) void scanB_kernel(int* __restrict__ bsum,
                                                    int* __restrict__ rowptr) {
  int g = blockIdx.x, t = threadIdx.x;
  int v = (t < NCH) ? bsum[g * NCH + t] : 0;
  __shared__ int sh[256];
  sh[t] = v;
  __syncthreads();
  for (int off = 1; off < 256; off <<= 1) {
    int x = (t >= off) ? sh[t - off] : 0;
    __syncthreads();
    if (t >= off) sh[t] += x;
    __syncthreads();
  }
  if (t < NCH) bsum[g * NCH + t] = sh[t] - v;  // exclusive base
  if (t == 255) rowptr[g * (NN + 1) + NN] = sh[255];
}

__global__ __launch_bounds__(256) void scanC_kernel(const int* __restrict__ counts,
                                                    const int* __restrict__ bsum,
                                                    int* __restrict__ rowptr,
                                                    int* __restrict__ cursor,
                                                    float* __restrict__ dinv) {
  int g = blockIdx.y, chunk = blockIdx.x, t = threadIdx.x;
  int i = chunk * 256 + t;
  int c = (i < NN) ? counts[g * NN + i] : 0;
  int v = (c + 7) & ~7;  // padded
  __shared__ int sh[256];
  sh[t] = v;
  __syncthreads();
  for (int off = 1; off < 256; off <<= 1) {
    int x = (t >= off) ? sh[t - off] : 0;
    __syncthreads();
    if (t >= off) sh[t] += x;
    __syncthreads();
  }
  if (i < NN) {
    int run = bsum[g * NCH + chunk] + sh[t] - v;
    rowptr[g * (NN + 1) + i] = run;
    cursor[g * NN + i] = run;
    dinv[g * NN + i] = rsqrtf((float)(c + 1));  // true degree +1 self-loop
  }
}

// ---------------- Pack W into B-fragment order ----------------
// Wpack flat index: ((kb*NT + nt)*64 + lane)*8 + j  holds W[kb*32 + (lane>>4)*8 + j][nt*16 + (lane&15)]

__global__ void pack_kernel(const float* __restrict__ W1, const float* __restrict__ W2,
                            unsigned short* __restrict__ P1, unsigned short* __restrict__ P2) {
  int i = blockIdx.x * blockDim.x + threadIdx.x;
  constexpr int N1 = 8 * 16 * 64 * 8;  // 65536 (K=256, N=256)
  constexpr int N2 = 8 * 8 * 64 * 8;   // 32768 (K=256, N=128)
  if (i < N1) {
    int j = i & 7, lane = (i >> 3) & 63, grp = i >> 9;
    int nt = grp & 15, kb = grp >> 4;
    int k = kb * 32 + (lane >> 4) * 8 + j;
    int n = nt * 16 + (lane & 15);
    P1[i] = f2bf(W1[k * DHID + n]);
  } else if (i < N1 + N2) {
    int ii = i - N1;
    int j = ii & 7, lane = (ii >> 3) & 63, grp = ii >> 9;
    int nt = grp & 7, kb = grp >> 3;
    int k = kb * 32 + (lane >> 4) * 8 + j;
    int n = nt * 16 + (lane & 15);
    P2[ii] = f2bf(W2[k * DOUT + n]);
  }
}

// ---------------- mm1: m1c = (x @ W1) * dinv[row], CHUNK-MAJOR bf16 ----------------
// Round-6 shape (64 rows/block, 256 thr) + per-K-step double-buffered LDS B tile:
// stage 16 KB slice of P1 for kb (each thread 4 x uint4), prefetch kb+1 while
// 4 waves MFMA kb from conflict-free ds_read_b128. A rows loaded once up-front.
// m1c layout: [g][chunk 0..7][node (NNP rows)][32 cols]; chunk = col>>5.

__global__ __launch_bounds__(256) void mm1_kernel(
    const float* __restrict__ A0, const float* __restrict__ A1,
    const unsigned short* __restrict__ Wp, unsigned short* __restrict__ m1c,
    const float* __restrict__ dinv) {
  constexpr int NT = 16, K = 256;
  constexpr int SLICE4 = NT * 64 * 8 / 8;  // 1024 uint4 per 16 KB slice
  __shared__ unsigned short Bsh[2][NT * 64 * 8];  // 2 x 16 KB
  int g = blockIdx.y;
  const float* A = g ? A1 : A0;
  unsigned short* C = m1c + (size_t)g * 8 * NNP * 32;
  const float* dv = dinv + g * NN;
  int wave = threadIdx.x >> 6, lane = threadIdx.x & 63;
  int q = lane >> 4, lm = lane & 15;
  int m0 = blockIdx.x * 64 + wave * 16;
  int rowc = min(m0 + lm, NN - 1);
  // A rows -> bf16 frags, loaded once
  bf16x8 af[8];
  const float* Ab = A + (size_t)rowc * K + q * 8;
#pragma unroll
  for (int kb = 0; kb < 8; kb++) {
    float4 v0 = *(const float4*)(Ab + kb * 32);
    float4 v1 = *(const float4*)(Ab + kb * 32 + 4);
    bf16x8 a;
    a[0] = (__bf16)v0.x; a[1] = (__bf16)v0.y; a[2] = (__bf16)v0.z; a[3] = (__bf16)v0.w;
    a[4] = (__bf16)v1.x; a[5] = (__bf16)v1.y; a[6] = (__bf16)v1.z; a[7] = (__bf16)v1.w;
    af[kb] = a;
  }
  // stage kb=0 slice
  {
    const uint4* src = (const uint4*)Wp;
    uint4* dst = (uint4*)Bsh[0];
#pragma unroll
    for (int u = 0; u < 4; u++) dst[threadIdx.x * 4 + u] = src[threadIdx.x * 4 + u];
  }
  f32x4 acc[NT];
#pragma unroll
  for (int nt = 0; nt < NT; nt++) acc[nt] = (f32x4){0.f, 0.f, 0.f, 0.f};
  for (int kb = 0; kb < 8; kb++) {
    __syncthreads();
    int cur = kb & 1;
    if (kb < 7) {  // prefetch next slice into other buffer
      const uint4* src = (const uint4*)Wp + (size_t)(kb + 1) * SLICE4;
      uint4* dst = (uint4*)Bsh[cur ^ 1];
#pragma unroll
      for (int u = 0; u < 4; u++) dst[threadIdx.x * 4 + u] = src[threadIdx.x * 4 + u];
    }
#pragma unroll
    for (int nt = 0; nt < NT; nt++) {
      bf16x8 b = *(const bf16x8*)(Bsh[cur] + (nt * 64 + lane) * 8);
      acc[nt] = __builtin_amdgcn_mfma_f32_16x16x32_bf16(af[kb], b, acc[nt], 0, 0, 0);
    }
  }
  float dvr[4];
#pragma unroll
  for (int r = 0; r < 4; r++) dvr[r] = dv[min(m0 + q * 4 + r, NN - 1)];
#pragma unroll
  for (int nt = 0; nt < NT; nt++) {
#pragma unroll
    for (int r = 0; r < 4; r++) {
      int grow = m0 + q * 4 + r;
      if (grow < NN)
        C[((size_t)(nt >> 1) * NNP + grow) * 32 + (nt & 1) * 16 + lm] =
            f2bf(acc[nt][r] * dvr[r]);
    }
  }
}

// ---------------- agg1c: XCD-sharded group-per-node gather (32-col chunk) --------

__global__ __launch_bounds__(256) void agg1c_kernel(
    const unsigned short* __restrict__ m1c, unsigned short* __restrict__ a1c,
    const int* __restrict__ rowptr, const unsigned short* __restrict__ col,
    const float* __restrict__ dinv, const float* __restrict__ b1) {
  int chunk = blockIdx.x & 7, nb = blockIdx.x >> 3, g = blockIdx.y;
  const unsigned short* Hc = m1c + ((size_t)g * 8 + chunk) * ((size_t)NNP * 32);
  unsigned short* Ac = a1c + ((size_t)g * 8 + chunk) * ((size_t)NNP * 32);
  const int* rp = rowptr + g * (NN + 1);
  const unsigned short* cl = col + (size_t)g * NEP;
  const float* dv = dinv + g * NN;
  int lane = threadIdx.x & 63, wave = threadIdx.x >> 6;
  int sub = lane & 3;
  int node = nb * 64 + wave * 16 + (lane >> 2);
  int nodec = min(node, NN - 1);
  float4 bb0 = *(const float4*)(b1 + chunk * 32 + sub * 8);
  float4 bb1 = *(const float4*)(b1 + chunk * 32 + sub * 8 + 4);
  int jb = rp[nodec], je = rp[nodec + 1];
  float a[8] = {0.f, 0.f, 0.f, 0.f, 0.f, 0.f, 0.f, 0.f};
  // self row
  uint4 sv = *(const uint4*)(Hc + (size_t)nodec * 32 + sub * 8);
  acc8(a, sv);
  for (int j = jb; j < je; j += 8) {
    uint4 w = *(const uint4*)(cl + j);  // 8 indices, 16B aligned (jb,j mult of 8)
    int s0 = w.x & 0xffff, s1 = w.x >> 16;
    int s2 = w.y & 0xffff, s3 = w.y >> 16;
    int s4 = w.z & 0xffff, s5 = w.z >> 16;
    int s6 = w.w & 0xffff, s7 = w.w >> 16;
    uint4 v0 = *(const uint4*)(Hc + s0 * 32 + sub * 8);
    uint4 v1 = *(const uint4*)(Hc + s1 * 32 + sub * 8);
    uint4 v2 = *(const uint4*)(Hc + s2 * 32 + sub * 8);
    uint4 v3 = *(const uint4*)(Hc + s3 * 32 + sub * 8);
    uint4 v4 = *(const uint4*)(Hc + s4 * 32 + sub * 8);
    uint4 v5 = *(const uint4*)(Hc + s5 * 32 + sub * 8);
    uint4 v6 = *(const uint4*)(Hc + s6 * 32 + sub * 8);
    uint4 v7 = *(const uint4*)(Hc + s7 * 32 + sub * 8);
    acc8(a, v0); acc8(a, v1); acc8(a, v2); acc8(a, v3);
    acc8(a, v4); acc8(a, v5); acc8(a, v6); acc8(a, v7);
  }
  float di = dv[nodec];
  us8 o;
  o[0] = f2bf(fmaxf(fmaf(a[0], di, bb0.x), 0.f));
  o[1] = f2bf(fmaxf(fmaf(a[1], di, bb0.y), 0.f));
  o[2] = f2bf(fmaxf(fmaf(a[2], di, bb0.z), 0.f));
  o[3] = f2bf(fmaxf(fmaf(a[3], di, bb0.w), 0.f));
  o[4] = f2bf(fmaxf(fmaf(a[4], di, bb1.x), 0.f));
  o[5] = f2bf(fmaxf(fmaf(a[5], di, bb1.y), 0.f));
  o[6] = f2bf(fmaxf(fmaf(a[6], di, bb1.z), 0.f));
  o[7] = f2bf(fmaxf(fmaf(a[7], di, bb1.w), 0.f));
  if (node < NN) *(us8*)(Ac + (size_t)node * 32 + sub * 8) = o;
}

// ---------------- mm2: m2c = (a1 @ W2) * dinv, dense GEMM ----------------
// Round-6 shape + per-K-step double-buffered LDS B tile (8 KB slices).
// a1c chunk-major IS the A-frag layout. m2c chunk-major: [g][chunk 0..3][node][32].

__global__ __launch_bounds__(256) void mm2_kernel(
    const unsigned short* __restrict__ a1c, const unsigned short* __restrict__ P2,
    unsigned short* __restrict__ m2c, const float* __restrict__ dinv) {
  constexpr int NT2 = DOUT / 16;  // 8
  constexpr int SLICE4 = NT2 * 64 * 8 / 8;  // 512 uint4 per 8 KB slice
  __shared__ unsigned short Bsh[2][NT2 * 64 * 8];  // 2 x 8 KB
  int g = blockIdx.y;
  const unsigned short* A = a1c + (size_t)g * 8 * NNP * 32;
  unsigned short* C = m2c + (size_t)g * 4 * NNP * 32;
  const float* dv = dinv + g * NN;
  int wave = threadIdx.x >> 6, lane = threadIdx.x & 63;
  int q = lane >> 4, lm = lane & 15;
  int m0 = blockIdx.x * 64 + wave * 16;
  int rowc = min(m0 + lm, NN - 1);
  bf16x8 af[8];
#pragma unroll
  for (int kb = 0; kb < 8; kb++)
    af[kb] = *(const bf16x8*)(A + ((size_t)kb * NNP + rowc) * 32 + q * 8);
  {
    const uint4* src = (const uint4*)P2;
    uint4* dst = (uint4*)Bsh[0];
#pragma unroll
    for (int u = 0; u < 2; u++) dst[threadIdx.x * 2 + u] = src[threadIdx.x * 2 + u];
  }
  f32x4 acc[NT2];
#pragma unroll
  for (int nt = 0; nt < NT2; nt++) acc[nt] = (f32x4){0.f, 0.f, 0.f, 0.f};
  for (int kb = 0; kb < 8; kb++) {
    __syncthreads();
    int cur = kb & 1;
    if (kb < 7) {
      const uint4* src = (const uint4*)P2 + (size_t)(kb + 1) * SLICE4;
      uint4* dst = (uint4*)Bsh[cur ^ 1];
#pragma unroll
      for (int u = 0; u < 2; u++) dst[threadIdx.x * 2 + u] = src[threadIdx.x * 2 + u];
    }
#pragma unroll
    for (int nt = 0; nt < NT2; nt++) {
      bf16x8 b = *(const bf16x8*)(Bsh[cur] + (nt * 64 + lane) * 8);
      acc[nt] = __builtin_amdgcn_mfma_f32_16x16x32_bf16(af[kb], b, acc[nt], 0, 0, 0);
    }
  }
  float dvr[4];
#pragma unroll
  for (int r = 0; r < 4; r++) dvr[r] = dv[min(m0 + q * 4 + r, NN - 1)];
#pragma unroll
  for (int nt = 0; nt < NT2; nt++) {
#pragma unroll
    for (int r = 0; r < 4; r++) {
      int grow = m0 + q * 4 + r;
      if (grow < NN)
        C[((size_t)(nt >> 1) * NNP + grow) * 32 + (nt & 1) * 16 + lm] =
            f2bf(acc[nt][r] * dvr[r]);
    }
  }
}

// ---------------- agg2c: XCD-sharded group-per-node final aggregate -> out ------

__global__ __launch_bounds__(256) void agg2c_kernel(
    const unsigned short* __restrict__ m2c, float* __restrict__ out,
    const int* __restrict__ rowptr, const unsigned short* __restrict__ col,
    const float* __restrict__ dinv, const float* __restrict__ b2) {
  int chunk = blockIdx.x & 3, nb = blockIdx.x >> 2, g = blockIdx.y;
  const unsigned short* Hc = m2c + ((size_t)g * 4 + chunk) * ((size_t)NNP * 32);
  float* O = out + (size_t)g * NN * DOUT;
  const int* rp = rowptr + g * (NN + 1);
  const unsigned short* cl = col + (size_t)g * NEP;
  const float* dv = dinv + g * NN;
  int lane = threadIdx.x & 63, wave = threadIdx.x >> 6;
  int sub = lane & 3;
  int node = nb * 64 + wave * 16 + (lane >> 2);
  int nodec = min(node, NN - 1);
  float4 c0 = *(const float4*)(b2 + chunk * 32 + sub * 8);
  float4 c1 = *(const float4*)(b2 + chunk * 32 + sub * 8 + 4);
  int jb = rp[nodec], je = rp[nodec + 1];
  float a[8] = {0.f, 0.f, 0.f, 0.f, 0.f, 0.f, 0.f, 0.f};
  uint4 sv = *(const uint4*)(Hc + (size_t)nodec * 32 + sub * 8);
  acc8(a, sv);
  for (int j = jb; j < je; j += 8) {
    uint4 w = *(const uint4*)(cl + j);
    int s0 = w.x & 0xffff, s1 = w.x >> 16;
    int s2 = w.y & 0xffff, s3 = w.y >> 16;
    int s4 = w.z & 0xffff, s5 = w.z >> 16;
    int s6 = w.w & 0xffff, s7 = w.w >> 16;
    uint4 v0 = *(const uint4*)(Hc + s0 * 32 + sub * 8);
    uint4 v1 = *(const uint4*)(Hc + s1 * 32 + sub * 8);
    uint4 v2 = *(const uint4*)(Hc + s2 * 32 + sub * 8);
    uint4 v3 = *(const uint4*)(Hc + s3 * 32 + sub * 8);
    uint4 v4 = *(const uint4*)(Hc + s4 * 32 + sub * 8);
    uint4 v5 = *(const uint4*)(Hc + s5 * 32 + sub * 8);
    uint4 v6 = *(const uint4*)(Hc + s6 * 32 + sub * 8);
    uint4 v7 = *(const uint4*)(Hc + s7 * 32 + sub * 8);
    acc8(a, v0); acc8(a, v1); acc8(a, v2); acc8(a, v3);
    acc8(a, v4); acc8(a, v5); acc8(a, v6); acc8(a, v7);
  }
  if (node < NN) {
    float di = dv[node];
    float4 o0, o1;
    o0.x = fmaf(a[0], di, c0.x); o0.y = fmaf(a[1], di, c0.y);
    o0.z = fmaf(a[2], di, c0.z); o0.w = fmaf(a[3], di, c0.w);
    o1.x = fmaf(a[4], di, c1.x); o1.y = fmaf(a[5], di, c1.y);
    o1.z = fmaf(a[6], di, c1.z); o1.w = fmaf(a[7], di, c1.w);
    *(float4*)(O + (size_t)node * DOUT + chunk * 32 + sub * 8) = o0;
    *(float4*)(O + (size_t)node * DOUT + chunk * 32 + sub * 8 + 4) = o1;
  }
}

// ---------------- launch ----------------

extern "C" void kernel_launch(void* const* d_in, const int* in_sizes, int n_in,
                              void* d_out, int out_size, void* d_ws, size_t ws_size,
                              hipStream_t stream) {
  const float* x1 = (const float*)d_in[0];
  const int* e1 = (const int*)d_in[1];
  const float* x2 = (const float*)d_in[2];
  const int* e2 = (const int*)d_in[3];
  const float* W1 = (const float*)d_in[4];
  const float* b1 = (const float*)d_in[5];
  const float* W2 = (const float*)d_in[6];
  const float* b2 = (const float*)d_in[7];
  float* out = (float*)d_out;

  char* base = (char*)d_ws;
  size_t off = 0;
  auto alloc = [&](size_t bytes) -> void* {
    void* p = base + off;
    off = (off + bytes + 511) & ~(size_t)511;
    return p;
  };
  int* counts = (int*)alloc((size_t)2 * NN * 4);
  int* rowptr = (int*)alloc((size_t)2 * (NN + 1) * 4);
  int* cursor = (int*)alloc((size_t)2 * NN * 4);
  float* dinv = (float*)alloc((size_t)2 * NN * 4);
  int* bsum = (int*)alloc((size_t)2 * NCH * 4);
  unsigned short* col = (unsigned short*)alloc((size_t)2 * NEP * 2);
  unsigned short* m1c = (unsigned short*)alloc((size_t)2 * 8 * NNP * 32 * 2);
  unsigned short* a1c = (unsigned short*)alloc((size_t)2 * 8 * NNP * 32 * 2);
  unsigned short* m2c = m1c;  // reuse: m1c dead after agg1c; zero rows preserved
  unsigned short* P1 = (unsigned short*)alloc((size_t)8 * 16 * 64 * 8 * 2);
  unsigned short* P2 = (unsigned short*)alloc((size_t)8 * 8 * 64 * 8 * 2);

  fillcol_kernel<<<(2 * NEP / 8 + 255) / 256, 256, 0, stream>>>(col);
  hipMemsetAsync(counts, 0, (size_t)2 * NN * 4, stream);
  // XCD-partitioned hist: 8 ranges x 96 slices
  hist_kernel<<<dim3(8 * 96, 2), 256, 0, stream>>>(e1, e2, counts);
  scanA_kernel<<<dim3(NCH, 2), 256, 0, stream>>>(counts, bsum);
  scanB_kernel<<<2, 256, 0, stream>>>(bsum, rowptr);
  scanC_kernel<<<dim3(NCH, 2), 256, 0, stream>>>(counts, bsum, rowptr, cursor, dinv);
  // XCD-partitioned scatter: cursor + cl region per dst-range stay in one L2
  scatter_kernel<<<dim3(8 * 96, 2), 256, 0, stream>>>(e1, e2, cursor, col);
  pack_kernel<<<(98304 + 255) / 256, 256, 0, stream>>>(W1, W2, P1, P2);
  zrow_kernel<<<1, 512, 0, stream>>>(m1c);
  // layer 1 mm: m1c = (x @ W1) * dinv (bf16, chunk-major), dbl-buffered B tiles
  mm1_kernel<<<dim3(NGRP, 2), 256, 0, stream>>>(x1, x2, P1, m1c, dinv);
  // sharded agg1: a1c = relu(agg(m1c)*dinv + b1) per 32-col chunk (XCD-local)
  agg1c_kernel<<<dim3(8 * NGRP, 2), 256, 0, stream>>>(m1c, a1c, rowptr, col, dinv, b1);
  // layer 2 mm: m2c = (a1 @ W2) * dinv (bf16, chunk-major), dbl-buffered B tiles
  mm2_kernel<<<dim3(NGRP, 2), 256, 0, stream>>>(a1c, P2, m2c, dinv);
  // sharded agg2: out = agg(m2c)*dinv + b2 (f32)
  agg2c_kernel<<<dim3(4 * NGRP, 2), 256, 0, stream>>>(m2c, out, rowptr, col, dinv, b2);
}